// Round 1
// baseline (341.000 us; speedup 1.0000x reference)
//
#include <hip/hip_runtime.h>
#include <hip/hip_bf16.h>

#define AS1 __attribute__((address_space(1)))
#define AS3 __attribute__((address_space(3)))

typedef __bf16 bf16_8 __attribute__((ext_vector_type(8)));
typedef float f32x4 __attribute__((ext_vector_type(4)));

constexpr int Tn = 4096;   // B*S tokens
constexpr int Hn = 1024;   // hidden
constexpr int Dn = 1024;   // expert inner dim
constexpr int En = 8;      // experts
constexpr float kAlpha = 1.702f;
constexpr float kLimit = 7.0f;

// f32 -> bf16 round-to-nearest-even (bit trick; no NaN inputs expected)
__device__ __forceinline__ unsigned short f2bf(float x) {
  unsigned u = __builtin_bit_cast(unsigned, x);
  u = u + 0x7FFFu + ((u >> 16) & 1u);
  return (unsigned short)(u >> 16);
}

// async global->LDS, 16B per lane. lds ptr must be wave-uniform; HW adds lane*16.
__device__ __forceinline__ void gload_lds16(const void* gp, void* lp) {
  __builtin_amdgcn_global_load_lds(
      (const AS1 unsigned int*)(unsigned long long)gp,
      (AS3 unsigned int*)(unsigned int)(unsigned long long)lp,
      16, 0, 0);
}

// ---- w[t][e] = routing_weights[t][e] * count(router_indices[t]==e) ----
__global__ void k_weights(const int* __restrict__ ridx, const float* __restrict__ rw,
                          float* __restrict__ w) {
  int i = blockIdx.x * blockDim.x + threadIdx.x;
  if (i >= Tn * En) return;
  int t = i >> 3, e = i & 7;
  int c = (ridx[t * 2] == e) + (ridx[t * 2 + 1] == e);
  w[i] = rw[i] * (float)c;
}

// ---- X f32 -> bf16, vectorized ----
__global__ void k_cvt_x(const float* __restrict__ x, unsigned short* __restrict__ xb) {
  int i = blockIdx.x * blockDim.x + threadIdx.x;  // exact grid, 4 elems each
  float4 v = reinterpret_cast<const float4*>(x)[i];
  ushort4 o;
  o.x = f2bf(v.x); o.y = f2bf(v.y); o.z = f2bf(v.z); o.w = f2bf(v.w);
  reinterpret_cast<ushort4*>(xb)[i] = o;
}

// ---- transpose + deinterleave gate_up_proj[e][h][2d|2d+1] -> Wg[e][d][h], Wu[e][d][h] bf16 ----
__global__ void k_t_gu(const float* __restrict__ gup, unsigned short* __restrict__ wg,
                       unsigned short* __restrict__ wu) {
  __shared__ float lg[32][33], lu[32][33];
  int e = blockIdx.z, h0 = blockIdx.y * 32, d0 = blockIdx.x * 32;
  int tx = threadIdx.x, ty0 = threadIdx.y;
  const float* src = gup + ((size_t)e * Hn + h0) * (2 * Dn) + d0 * 2;
#pragma unroll
  for (int k = 0; k < 4; k++) {
    int ty = ty0 + k * 8;
    float2 v = *reinterpret_cast<const float2*>(src + (size_t)ty * (2 * Dn) + tx * 2);
    lg[ty][tx] = v.x;  lu[ty][tx] = v.y;
  }
  __syncthreads();
  unsigned short* dg = wg + ((size_t)e * Dn + d0) * Hn + h0;
  unsigned short* du = wu + ((size_t)e * Dn + d0) * Hn + h0;
#pragma unroll
  for (int k = 0; k < 4; k++) {
    int r = ty0 + k * 8;
    dg[(size_t)r * Hn + tx] = f2bf(lg[tx][r]);
    du[(size_t)r * Hn + tx] = f2bf(lu[tx][r]);
  }
}

// ---- transpose down_proj[e][d][h] -> Wd_t[e][h][d] bf16 ----
__global__ void k_t_dn(const float* __restrict__ dwn, unsigned short* __restrict__ wdt) {
  __shared__ float ls[32][33];
  int e = blockIdx.z, d0 = blockIdx.y * 32, h0 = blockIdx.x * 32;
  int tx = threadIdx.x, ty0 = threadIdx.y;
  const float* src = dwn + ((size_t)e * Dn + d0) * Hn + h0;
#pragma unroll
  for (int k = 0; k < 4; k++) { int ty = ty0 + k * 8; ls[ty][tx] = src[(size_t)ty * Hn + tx]; }
  __syncthreads();
  unsigned short* dst = wdt + ((size_t)e * Hn + h0) * Dn + d0;
#pragma unroll
  for (int k = 0; k < 4; k++) { int r = ty0 + k * 8; dst[(size_t)r * Dn + tx] = f2bf(ls[tx][r]); }
}

// ---- out[t][h] = sum_e w[t][e] * down_bias[e][h] ----
__global__ void k_bias(const float* __restrict__ w, const float* __restrict__ db,
                       float* __restrict__ out) {
  int i = blockIdx.x * blockDim.x + threadIdx.x;
  if (i >= Tn * Hn) return;
  int t = i >> 10, h = i & (Hn - 1);
  const float* wr = w + t * En;
  float acc = 0.f;
#pragma unroll
  for (int e = 0; e < En; e++) acc += wr[e] * db[e * Hn + h];
  out[i] = acc;
}

// ---- GEMM1 + activation: midw[t][e*Dn+d] = w[t,e] * act(X@Wg/Wu + bias)  (bf16) ----
// BM=128, BN=64 (d), BK=64; 4 waves, each 64x32 with dual accumulators (gate,up).
__launch_bounds__(256, 2)
__global__ void k_gemm1(const unsigned short* __restrict__ xb,
                        const unsigned short* __restrict__ wg,
                        const unsigned short* __restrict__ wu,
                        const float* __restrict__ gub,
                        const float* __restrict__ w,
                        unsigned short* __restrict__ midw) {
  constexpr int BM = 128, BN = 64, BK = 64;
  __shared__ __align__(16) unsigned short Xs[BM * BK];
  __shared__ __align__(16) unsigned short Gs[BN * BK];
  __shared__ __align__(16) unsigned short Us[BN * BK];
  const int e = blockIdx.z;
  const int m0 = blockIdx.x * BM;
  const int n0 = blockIdx.y * BN;
  const int tid = threadIdx.x;
  const int wv = tid >> 6, lane = tid & 63;
  const int wr = wv >> 1, wc = wv & 1;
  const int r8 = lane >> 3, c8 = lane & 7;

  const unsigned short* Ap = xb + (size_t)m0 * Hn;
  const unsigned short* Gp = wg + ((size_t)e * Dn + n0) * Hn;
  const unsigned short* Up = wu + ((size_t)e * Dn + n0) * Hn;

  f32x4 ag[4][2], au[4][2];
#pragma unroll
  for (int i = 0; i < 4; i++)
#pragma unroll
    for (int j = 0; j < 2; j++) { ag[i][j] = f32x4{0.f,0.f,0.f,0.f}; au[i][j] = f32x4{0.f,0.f,0.f,0.f}; }

  for (int k0 = 0; k0 < Hn; k0 += BK) {
#pragma unroll
    for (int c = 0; c < 4; c++) {
      int ch = c * 4 + wv;  // 16 chunks of 8 rows
      gload_lds16(Ap + (size_t)(ch * 8 + r8) * Hn + k0 + c8 * 8, (void*)(Xs + ch * 512));
    }
#pragma unroll
    for (int c = 0; c < 2; c++) {
      int ch = c * 4 + wv;  // 8 chunks
      gload_lds16(Gp + (size_t)(ch * 8 + r8) * Hn + k0 + c8 * 8, (void*)(Gs + ch * 512));
      gload_lds16(Up + (size_t)(ch * 8 + r8) * Hn + k0 + c8 * 8, (void*)(Us + ch * 512));
    }
    asm volatile("s_waitcnt vmcnt(0)" ::: "memory");
    __syncthreads();
    const int fr = lane & 15, kg = lane >> 4;
#pragma unroll
    for (int kk = 0; kk < 2; kk++) {
      bf16_8 a[4], bg[2], bu[2];
#pragma unroll
      for (int i = 0; i < 4; i++)
        a[i] = *reinterpret_cast<const bf16_8*>(Xs + (wr * 64 + i * 16 + fr) * BK + kk * 32 + kg * 8);
#pragma unroll
      for (int j = 0; j < 2; j++) {
        bg[j] = *reinterpret_cast<const bf16_8*>(Gs + (wc * 32 + j * 16 + fr) * BK + kk * 32 + kg * 8);
        bu[j] = *reinterpret_cast<const bf16_8*>(Us + (wc * 32 + j * 16 + fr) * BK + kk * 32 + kg * 8);
      }
#pragma unroll
      for (int i = 0; i < 4; i++)
#pragma unroll
        for (int j = 0; j < 2; j++) {
          ag[i][j] = __builtin_amdgcn_mfma_f32_16x16x32_bf16(a[i], bg[j], ag[i][j], 0, 0, 0);
          au[i][j] = __builtin_amdgcn_mfma_f32_16x16x32_bf16(a[i], bu[j], au[i][j], 0, 0, 0);
        }
    }
    __syncthreads();
  }

  const int fr = lane & 15, rg = lane >> 4;
#pragma unroll
  for (int i = 0; i < 4; i++) {
#pragma unroll
    for (int r = 0; r < 4; r++) {
      int row = m0 + wr * 64 + i * 16 + rg * 4 + r;
      float wt = w[row * En + e];
#pragma unroll
      for (int j = 0; j < 2; j++) {
        int d = n0 + wc * 32 + j * 16 + fr;
        float g = ag[i][j][r] + gub[e * 2 * Dn + 2 * d];
        float u = au[i][j][r] + gub[e * 2 * Dn + 2 * d + 1];
        g = fminf(g, kLimit);
        u = fminf(fmaxf(u, -kLimit), kLimit);
        float sg = 1.0f / (1.0f + __expf(-kAlpha * g));
        float mid = (u + 1.0f) * g * sg;
        midw[(size_t)row * (En * Dn) + e * Dn + d] = f2bf(wt * mid);
      }
    }
  }
}

// ---- GEMM2: out[t][h] += midw[T][8192] @ Wd_cat[8192][1024] ----
__launch_bounds__(256, 2)
__global__ void k_gemm2(const unsigned short* __restrict__ midw,
                        const unsigned short* __restrict__ wdt,
                        float* __restrict__ out) {
  constexpr int BM = 128, BN = 64, BK = 64, KK = En * Dn;  // 8192
  __shared__ __align__(16) unsigned short As[BM * BK];
  __shared__ __align__(16) unsigned short Bs[BN * BK];
  const int m0 = blockIdx.x * BM, n0 = blockIdx.y * BN;
  const int tid = threadIdx.x;
  const int wv = tid >> 6, lane = tid & 63;
  const int wr = wv >> 1, wc = wv & 1;
  const int r8 = lane >> 3, c8 = lane & 7;
  const unsigned short* Ap = midw + (size_t)m0 * KK;

  f32x4 acc[4][2];
#pragma unroll
  for (int i = 0; i < 4; i++)
#pragma unroll
    for (int j = 0; j < 2; j++) acc[i][j] = f32x4{0.f,0.f,0.f,0.f};

  for (int k0 = 0; k0 < KK; k0 += BK) {
    const unsigned short* Bp = wdt + ((size_t)(k0 >> 10) * Hn + n0) * Dn + (k0 & (Dn - 1));
#pragma unroll
    for (int c = 0; c < 4; c++) {
      int ch = c * 4 + wv;
      gload_lds16(Ap + (size_t)(ch * 8 + r8) * KK + k0 + c8 * 8, (void*)(As + ch * 512));
    }
#pragma unroll
    for (int c = 0; c < 2; c++) {
      int ch = c * 4 + wv;
      gload_lds16(Bp + (size_t)(ch * 8 + r8) * Dn + c8 * 8, (void*)(Bs + ch * 512));
    }
    asm volatile("s_waitcnt vmcnt(0)" ::: "memory");
    __syncthreads();
    const int fr = lane & 15, kg = lane >> 4;
#pragma unroll
    for (int kk = 0; kk < 2; kk++) {
      bf16_8 a[4], b[2];
#pragma unroll
      for (int i = 0; i < 4; i++)
        a[i] = *reinterpret_cast<const bf16_8*>(As + (wr * 64 + i * 16 + fr) * BK + kk * 32 + kg * 8);
#pragma unroll
      for (int j = 0; j < 2; j++)
        b[j] = *reinterpret_cast<const bf16_8*>(Bs + (wc * 32 + j * 16 + fr) * BK + kk * 32 + kg * 8);
#pragma unroll
      for (int i = 0; i < 4; i++)
#pragma unroll
        for (int j = 0; j < 2; j++)
          acc[i][j] = __builtin_amdgcn_mfma_f32_16x16x32_bf16(a[i], b[j], acc[i][j], 0, 0, 0);
    }
    __syncthreads();
  }

  const int fr = lane & 15, rg = lane >> 4;
#pragma unroll
  for (int i = 0; i < 4; i++)
#pragma unroll
    for (int r = 0; r < 4; r++) {
      int row = m0 + wr * 64 + i * 16 + rg * 4 + r;
#pragma unroll
      for (int j = 0; j < 2; j++) {
        int col = n0 + wc * 32 + j * 16 + fr;
        size_t o = (size_t)row * Hn + col;
        out[o] += acc[i][j][r];
      }
    }
}

extern "C" void kernel_launch(void* const* d_in, const int* in_sizes, int n_in,
                              void* d_out, int out_size, void* d_ws, size_t ws_size,
                              hipStream_t stream) {
  (void)in_sizes; (void)n_in; (void)out_size; (void)ws_size;
  const float* hs  = (const float*)d_in[0];
  const int*   ri  = (const int*)d_in[1];
  const float* rw  = (const float*)d_in[2];
  const float* gup = (const float*)d_in[3];
  const float* gub = (const float*)d_in[4];
  const float* dwn = (const float*)d_in[5];
  const float* db  = (const float*)d_in[6];
  float* out = (float*)d_out;

  char* ws = (char*)d_ws;
  float* w = (float*)ws;                                               // 128 KiB
  unsigned short* xb   = (unsigned short*)(ws + (size_t)131072);                       // 8 MiB
  unsigned short* wg   = (unsigned short*)(ws + (size_t)131072 + 8388608);             // 16 MiB
  unsigned short* wu   = (unsigned short*)(ws + (size_t)131072 + 8388608 + 16777216);  // 16 MiB
  unsigned short* wdt  = (unsigned short*)(ws + (size_t)131072 + 8388608 + 2*16777216);// 16 MiB
  unsigned short* midw = (unsigned short*)(ws + (size_t)131072 + 8388608 + 3*16777216);// 64 MiB

  k_weights<<<dim3((Tn * En + 255) / 256), dim3(256), 0, stream>>>(ri, rw, w);
  k_cvt_x<<<dim3(Tn * Hn / 4 / 256), dim3(256), 0, stream>>>(hs, xb);
  k_t_gu<<<dim3(Dn / 32, Hn / 32, En), dim3(32, 8), 0, stream>>>(gup, wg, wu);
  k_t_dn<<<dim3(Hn / 32, Dn / 32, En), dim3(32, 8), 0, stream>>>(dwn, wdt);
  k_bias<<<dim3(Tn * Hn / 256), dim3(256), 0, stream>>>(w, db, out);
  k_gemm1<<<dim3(Tn / 128, Dn / 64, En), dim3(256), 0, stream>>>(xb, wg, wu, gub, w, midw);
  k_gemm2<<<dim3(Tn / 128, Hn / 64), dim3(256), 0, stream>>>(midw, wdt, out);
}

// Round 2
// 163.146 us; speedup vs baseline: 2.0901x; 2.0901x over previous
//
#include <hip/hip_runtime.h>
#include <hip/hip_bf16.h>

#define AS1 __attribute__((address_space(1)))
#define AS3 __attribute__((address_space(3)))

typedef __bf16 bf16_8 __attribute__((ext_vector_type(8)));
typedef float f32x4 __attribute__((ext_vector_type(4)));

constexpr int Tn = 4096;   // B*S tokens
constexpr int Hn = 1024;   // hidden
constexpr int Dn = 1024;   // expert inner dim
constexpr int En = 8;      // experts
constexpr int Sn = 8192;   // routing slots = Tn*K
constexpr int Pmax = 9216; // max padded gathered rows (8192 + 8*128)
constexpr int MaxTiles = 72;
constexpr float kAlpha = 1.702f;
constexpr float kLimit = 7.0f;

// f32 -> bf16 round-to-nearest-even
__device__ __forceinline__ unsigned short f2bf(float x) {
  unsigned u = __builtin_bit_cast(unsigned, x);
  u = u + 0x7FFFu + ((u >> 16) & 1u);
  return (unsigned short)(u >> 16);
}

// async global->LDS, 16B per lane. lds ptr wave-uniform; HW adds lane*16.
__device__ __forceinline__ void gload_lds16(const void* gp, void* lp) {
  __builtin_amdgcn_global_load_lds(
      (const AS1 unsigned int*)(unsigned long long)gp,
      (AS3 unsigned int*)(unsigned int)(unsigned long long)lp,
      16, 0, 0);
}

// ---- X f32 -> bf16, vectorized ----
__global__ void k_cvt_x(const float* __restrict__ x, unsigned short* __restrict__ xb) {
  int i = blockIdx.x * blockDim.x + threadIdx.x;
  float4 v = reinterpret_cast<const float4*>(x)[i];
  ushort4 o;
  o.x = f2bf(v.x); o.y = f2bf(v.y); o.z = f2bf(v.z); o.w = f2bf(v.w);
  reinterpret_cast<ushort4*>(xb)[i] = o;
}

// ---- transpose + deinterleave gate_up_proj[e][h][2d|2d+1] -> Wg[e][d][h], Wu[e][d][h] bf16 ----
__global__ void k_t_gu(const float* __restrict__ gup, unsigned short* __restrict__ wg,
                       unsigned short* __restrict__ wu) {
  __shared__ float lg[32][33], lu[32][33];
  int e = blockIdx.z, h0 = blockIdx.y * 32, d0 = blockIdx.x * 32;
  int tx = threadIdx.x, ty0 = threadIdx.y;
  const float* src = gup + ((size_t)e * Hn + h0) * (2 * Dn) + d0 * 2;
#pragma unroll
  for (int k = 0; k < 4; k++) {
    int ty = ty0 + k * 8;
    float2 v = *reinterpret_cast<const float2*>(src + (size_t)ty * (2 * Dn) + tx * 2);
    lg[ty][tx] = v.x;  lu[ty][tx] = v.y;
  }
  __syncthreads();
  unsigned short* dg = wg + ((size_t)e * Dn + d0) * Hn + h0;
  unsigned short* du = wu + ((size_t)e * Dn + d0) * Hn + h0;
#pragma unroll
  for (int k = 0; k < 4; k++) {
    int r = ty0 + k * 8;
    dg[(size_t)r * Hn + tx] = f2bf(lg[tx][r]);
    du[(size_t)r * Hn + tx] = f2bf(lu[tx][r]);
  }
}

// ---- transpose down_proj[e][d][h] -> Wd_t[e][h][d] bf16 ----
__global__ void k_t_dn(const float* __restrict__ dwn, unsigned short* __restrict__ wdt) {
  __shared__ float ls[32][33];
  int e = blockIdx.z, d0 = blockIdx.y * 32, h0 = blockIdx.x * 32;
  int tx = threadIdx.x, ty0 = threadIdx.y;
  const float* src = dwn + ((size_t)e * Dn + d0) * Hn + h0;
#pragma unroll
  for (int k = 0; k < 4; k++) { int ty = ty0 + k * 8; ls[ty][tx] = src[(size_t)ty * Hn + tx]; }
  __syncthreads();
  unsigned short* dst = wdt + ((size_t)e * Hn + h0) * Dn + d0;
#pragma unroll
  for (int k = 0; k < 4; k++) { int r = ty0 + k * 8; dst[(size_t)r * Dn + tx] = f2bf(ls[tx][r]); }
}

// ---- routing: stable per-expert compaction of the 8192 (token,slot) pairs ----
// tix[p]   : token index feeding gathered row p (0-filled for padding)
// pos[s]   : gathered row of slot s
// tileE/P0 : per-128-row-tile expert id and base row; *ntiles tiles total
__global__ void k_route(const int* __restrict__ ridx,
                        int* __restrict__ tix, int* __restrict__ pos,
                        int* __restrict__ tileE, int* __restrict__ tileP0,
                        int* __restrict__ ntiles) {
  __shared__ int lh[256][8];   // per-thread-chunk histogram -> prefix
  __shared__ int eoff[8];
  int tid = threadIdx.x;
#pragma unroll
  for (int e = 0; e < 8; e++) lh[tid][e] = 0;
  int myE[32];
#pragma unroll
  for (int s = 0; s < 32; s++) {
    int e = ridx[tid * 32 + s];
    myE[s] = e;
    lh[tid][e]++;
  }
  __syncthreads();
  if (tid < 8) {   // exclusive prefix over the 256 chunks for expert `tid`
    int tot = 0;
#pragma unroll 1
    for (int t = 0; t < 256; t++) { int v = lh[t][tid]; lh[t][tid] = tot; tot += v; }
    eoff[tid] = tot;  // counts for now
  }
  __syncthreads();
  if (tid == 0) {
    int off = 0, nt = 0;
#pragma unroll 1
    for (int e = 0; e < 8; e++) {
      int cnt = eoff[e];
      eoff[e] = off;
      int nt128 = (cnt + 127) >> 7;
      for (int k = 0; k < nt128; k++) { tileE[nt] = e; tileP0[nt] = off + k * 128; nt++; }
      off += nt128 * 128;
    }
    *ntiles = nt;
  }
  __syncthreads();
  for (int p = tid; p < Pmax; p += 256) tix[p] = 0;  // padding rows -> token 0
  __syncthreads();
#pragma unroll
  for (int s = 0; s < 32; s++) {
    int slot = tid * 32 + s;
    int e = myE[s];
    int p = eoff[e] + (lh[tid][e]++);
    pos[slot] = p;
    tix[p] = slot >> 1;  // token index
  }
}

// ---- grouped GEMM1 + activation: midc[p][d] = act(x[tix[p]] @ [Wg|Wu]_e + bias) bf16 ----
__launch_bounds__(256, 2)
__global__ void k_gemm1(const unsigned short* __restrict__ xb,
                        const unsigned short* __restrict__ wg,
                        const unsigned short* __restrict__ wu,
                        const float* __restrict__ gub,
                        const int* __restrict__ tix,
                        const int* __restrict__ tileE,
                        const int* __restrict__ tileP0,
                        const int* __restrict__ ntiles,
                        unsigned short* __restrict__ midc) {
  constexpr int BM = 128, BN = 64, BK = 64;
  if ((int)blockIdx.x >= *ntiles) return;
  __shared__ __align__(16) unsigned short Xs[BM * BK];
  __shared__ __align__(16) unsigned short Gs[BN * BK];
  __shared__ __align__(16) unsigned short Us[BN * BK];
  const int e = tileE[blockIdx.x];
  const int p0 = tileP0[blockIdx.x];
  const int n0 = blockIdx.y * BN;
  const int tid = threadIdx.x;
  const int wv = tid >> 6, lane = tid & 63;
  const int wr = wv >> 1, wc = wv & 1;
  const int r8 = lane >> 3, c8 = lane & 7;

  int tokc[4];  // gathered token per A-staging chunk (invariant over k0)
#pragma unroll
  for (int c = 0; c < 4; c++) tokc[c] = tix[p0 + (c * 4 + wv) * 8 + r8];

  const unsigned short* Gp = wg + ((size_t)e * Dn + n0) * Hn;
  const unsigned short* Up = wu + ((size_t)e * Dn + n0) * Hn;

  f32x4 ag[4][2], au[4][2];
#pragma unroll
  for (int i = 0; i < 4; i++)
#pragma unroll
    for (int j = 0; j < 2; j++) { ag[i][j] = f32x4{0.f,0.f,0.f,0.f}; au[i][j] = f32x4{0.f,0.f,0.f,0.f}; }

  for (int k0 = 0; k0 < Hn; k0 += BK) {
#pragma unroll
    for (int c = 0; c < 4; c++) {
      int ch = c * 4 + wv;
      gload_lds16(xb + (size_t)tokc[c] * Hn + k0 + c8 * 8, (void*)(Xs + ch * 512));
    }
#pragma unroll
    for (int c = 0; c < 2; c++) {
      int ch = c * 4 + wv;
      gload_lds16(Gp + (size_t)(ch * 8 + r8) * Hn + k0 + c8 * 8, (void*)(Gs + ch * 512));
      gload_lds16(Up + (size_t)(ch * 8 + r8) * Hn + k0 + c8 * 8, (void*)(Us + ch * 512));
    }
    asm volatile("s_waitcnt vmcnt(0)" ::: "memory");
    __syncthreads();
    const int fr = lane & 15, kg = lane >> 4;
#pragma unroll
    for (int kk = 0; kk < 2; kk++) {
      bf16_8 a[4], bg[2], bu[2];
#pragma unroll
      for (int i = 0; i < 4; i++)
        a[i] = *reinterpret_cast<const bf16_8*>(Xs + (wr * 64 + i * 16 + fr) * BK + kk * 32 + kg * 8);
#pragma unroll
      for (int j = 0; j < 2; j++) {
        bg[j] = *reinterpret_cast<const bf16_8*>(Gs + (wc * 32 + j * 16 + fr) * BK + kk * 32 + kg * 8);
        bu[j] = *reinterpret_cast<const bf16_8*>(Us + (wc * 32 + j * 16 + fr) * BK + kk * 32 + kg * 8);
      }
#pragma unroll
      for (int i = 0; i < 4; i++)
#pragma unroll
        for (int j = 0; j < 2; j++) {
          ag[i][j] = __builtin_amdgcn_mfma_f32_16x16x32_bf16(a[i], bg[j], ag[i][j], 0, 0, 0);
          au[i][j] = __builtin_amdgcn_mfma_f32_16x16x32_bf16(a[i], bu[j], au[i][j], 0, 0, 0);
        }
    }
    __syncthreads();
  }

  const int fr = lane & 15, rg = lane >> 4;
#pragma unroll
  for (int i = 0; i < 4; i++) {
#pragma unroll
    for (int r = 0; r < 4; r++) {
      int row = p0 + wr * 64 + i * 16 + rg * 4 + r;
#pragma unroll
      for (int j = 0; j < 2; j++) {
        int d = n0 + wc * 32 + j * 16 + fr;
        float g = ag[i][j][r] + gub[e * 2 * Dn + 2 * d];
        float u = au[i][j][r] + gub[e * 2 * Dn + 2 * d + 1];
        g = fminf(g, kLimit);
        u = fminf(fmaxf(u, -kLimit), kLimit);
        float sg = 1.0f / (1.0f + __expf(-kAlpha * g));
        float mid = (u + 1.0f) * g * sg;
        midc[(size_t)row * Dn + d] = f2bf(mid);
      }
    }
  }
}

// ---- grouped GEMM2: ys[p][h] = midc[p][:] @ Wd_e  (f32 out, K=1024) ----
__launch_bounds__(256, 2)
__global__ void k_gemm2(const unsigned short* __restrict__ midc,
                        const unsigned short* __restrict__ wdt,
                        const int* __restrict__ tileE,
                        const int* __restrict__ tileP0,
                        const int* __restrict__ ntiles,
                        float* __restrict__ ys) {
  constexpr int BM = 128, BN = 64, BK = 64;
  if ((int)blockIdx.x >= *ntiles) return;
  __shared__ __align__(16) unsigned short As[BM * BK];
  __shared__ __align__(16) unsigned short Bs[BN * BK];
  const int e = tileE[blockIdx.x];
  const int p0 = tileP0[blockIdx.x];
  const int n0 = blockIdx.y * BN;
  const int tid = threadIdx.x;
  const int wv = tid >> 6, lane = tid & 63;
  const int wr = wv >> 1, wc = wv & 1;
  const int r8 = lane >> 3, c8 = lane & 7;
  const unsigned short* Ap = midc + (size_t)p0 * Dn;
  const unsigned short* Bp = wdt + ((size_t)e * Hn + n0) * Dn;

  f32x4 acc[4][2];
#pragma unroll
  for (int i = 0; i < 4; i++)
#pragma unroll
    for (int j = 0; j < 2; j++) acc[i][j] = f32x4{0.f,0.f,0.f,0.f};

  for (int k0 = 0; k0 < Dn; k0 += BK) {
#pragma unroll
    for (int c = 0; c < 4; c++) {
      int ch = c * 4 + wv;
      gload_lds16(Ap + (size_t)(ch * 8 + r8) * Dn + k0 + c8 * 8, (void*)(As + ch * 512));
    }
#pragma unroll
    for (int c = 0; c < 2; c++) {
      int ch = c * 4 + wv;
      gload_lds16(Bp + (size_t)(ch * 8 + r8) * Dn + k0 + c8 * 8, (void*)(Bs + ch * 512));
    }
    asm volatile("s_waitcnt vmcnt(0)" ::: "memory");
    __syncthreads();
    const int fr = lane & 15, kg = lane >> 4;
#pragma unroll
    for (int kk = 0; kk < 2; kk++) {
      bf16_8 a[4], b[2];
#pragma unroll
      for (int i = 0; i < 4; i++)
        a[i] = *reinterpret_cast<const bf16_8*>(As + (wr * 64 + i * 16 + fr) * BK + kk * 32 + kg * 8);
#pragma unroll
      for (int j = 0; j < 2; j++)
        b[j] = *reinterpret_cast<const bf16_8*>(Bs + (wc * 32 + j * 16 + fr) * BK + kk * 32 + kg * 8);
#pragma unroll
      for (int i = 0; i < 4; i++)
#pragma unroll
        for (int j = 0; j < 2; j++)
          acc[i][j] = __builtin_amdgcn_mfma_f32_16x16x32_bf16(a[i], b[j], acc[i][j], 0, 0, 0);
    }
    __syncthreads();
  }

  const int fr = lane & 15, rg = lane >> 4;
#pragma unroll
  for (int i = 0; i < 4; i++)
#pragma unroll
    for (int r = 0; r < 4; r++) {
      int row = p0 + wr * 64 + i * 16 + rg * 4 + r;
#pragma unroll
      for (int j = 0; j < 2; j++) {
        int col = n0 + wc * 32 + j * 16 + fr;
        ys[(size_t)row * Hn + col] = acc[i][j][r];
      }
    }
}

// ---- combine: out[t][h] = sum_k rw[t,e_k] * (ys[p_k][h] + db[e_k][h]) ----
__global__ void k_combine(const float* __restrict__ ys, const int* __restrict__ ridx,
                          const float* __restrict__ rw, const int* __restrict__ pos,
                          const float* __restrict__ db, float* __restrict__ out) {
  int t = blockIdx.x;
  int h0 = threadIdx.x * 4;
  int e0 = ridx[2 * t], e1 = ridx[2 * t + 1];
  int p0 = pos[2 * t], p1 = pos[2 * t + 1];
  float w0 = rw[t * En + e0], w1 = rw[t * En + e1];
  float4 y0 = *reinterpret_cast<const float4*>(ys + (size_t)p0 * Hn + h0);
  float4 y1 = *reinterpret_cast<const float4*>(ys + (size_t)p1 * Hn + h0);
  float4 b0 = *reinterpret_cast<const float4*>(db + (size_t)e0 * Hn + h0);
  float4 b1 = *reinterpret_cast<const float4*>(db + (size_t)e1 * Hn + h0);
  float4 o;
  o.x = w0 * (y0.x + b0.x) + w1 * (y1.x + b1.x);
  o.y = w0 * (y0.y + b0.y) + w1 * (y1.y + b1.y);
  o.z = w0 * (y0.z + b0.z) + w1 * (y1.z + b1.z);
  o.w = w0 * (y0.w + b0.w) + w1 * (y1.w + b1.w);
  *reinterpret_cast<float4*>(out + (size_t)t * Hn + h0) = o;
}

extern "C" void kernel_launch(void* const* d_in, const int* in_sizes, int n_in,
                              void* d_out, int out_size, void* d_ws, size_t ws_size,
                              hipStream_t stream) {
  (void)in_sizes; (void)n_in; (void)out_size; (void)ws_size;
  const float* hs  = (const float*)d_in[0];
  const int*   ri  = (const int*)d_in[1];
  const float* rw  = (const float*)d_in[2];
  const float* gup = (const float*)d_in[3];
  const float* gub = (const float*)d_in[4];
  const float* dwn = (const float*)d_in[5];
  const float* db  = (const float*)d_in[6];
  float* out = (float*)d_out;

  char* ws = (char*)d_ws;
  int* tix    = (int*)(ws);                       // 36 KiB (Pmax)
  int* pos    = (int*)(ws + 65536);               // 32 KiB
  int* tileE  = (int*)(ws + 131072);              // 512 B
  int* tileP0 = (int*)(ws + 131584);              // 512 B
  int* ntiles = (int*)(ws + 132096);              // 4 B
  unsigned short* xb   = (unsigned short*)(ws + 262144);                 // 8 MiB
  unsigned short* wg   = (unsigned short*)(ws + 262144 + 8388608);       // 16 MiB
  unsigned short* wu   = (unsigned short*)(ws + 262144 + 8388608 + 16777216);        // 16 MiB
  unsigned short* wdt  = (unsigned short*)(ws + 262144 + 8388608 + 2*16777216);      // 16 MiB
  unsigned short* midc = (unsigned short*)(ws + 262144 + 8388608 + 3*16777216);      // 18 MiB (Pmax x Dn bf16)
  float* ys            = (float*)(ws + 262144 + 8388608 + 3*16777216 + (size_t)Pmax * Dn * 2);  // 36 MiB

  k_route<<<dim3(1), dim3(256), 0, stream>>>(ri, tix, pos, tileE, tileP0, ntiles);
  k_cvt_x<<<dim3(Tn * Hn / 4 / 256), dim3(256), 0, stream>>>(hs, xb);
  k_t_gu<<<dim3(Dn / 32, Hn / 32, En), dim3(32, 8), 0, stream>>>(gup, wg, wu);
  k_t_dn<<<dim3(Hn / 32, Dn / 32, En), dim3(32, 8), 0, stream>>>(dwn, wdt);
  k_gemm1<<<dim3(MaxTiles, Dn / 64), dim3(256), 0, stream>>>(xb, wg, wu, gub, tix, tileE, tileP0, ntiles, midc);
  k_gemm2<<<dim3(MaxTiles, Hn / 64), dim3(256), 0, stream>>>(midc, wdt, tileE, tileP0, ntiles, ys);
  k_combine<<<dim3(Tn), dim3(256), 0, stream>>>(ys, ri, rw, pos, db, out);
}